// Round 1
// baseline (151.271 us; speedup 1.0000x reference)
//
#include <hip/hip_runtime.h>
#include <stdint.h>

typedef __bf16 bf16x8 __attribute__((ext_vector_type(8)));
typedef float  f32x4  __attribute__((ext_vector_type(4)));

#define MFMA(a,b,c) __builtin_amdgcn_mfma_f32_16x16x32_bf16((a),(b),(c),0,0,0)

// float -> bf16 bits, round-to-nearest-even (inputs finite)
__device__ __forceinline__ short f2b(float x) {
  uint32_t u = __float_as_uint(x);
  uint32_t r = (u + 0x7fffu + ((u >> 16) & 1u)) >> 16;
  return (short)r;
}

// ---------------- prep: weights->bf16, posT, BN constants ----------------
__global__ void k_prep(const float* __restrict__ w1, const float* __restrict__ wq,
                       const float* __restrict__ wk, const float* __restrict__ wv,
                       const float* __restrict__ w2,
                       const float* __restrict__ relh, const float* __restrict__ relw,
                       const float* __restrict__ g1, const float* __restrict__ b1,
                       const float* __restrict__ m1, const float* __restrict__ v1,
                       const float* __restrict__ g2, const float* __restrict__ b2,
                       const float* __restrict__ m2, const float* __restrict__ v2,
                       short* __restrict__ w1b, short* __restrict__ wqb,
                       short* __restrict__ wkb, short* __restrict__ wvb,
                       short* __restrict__ w2b, short* __restrict__ posT,
                       float* __restrict__ bnc) {
  int i = blockIdx.x * 256 + threadIdx.x;
  if (i < 32768) { w1b[i] = f2b(w1[i]); return; }
  i -= 32768;
  if (i < 16384) { wqb[i] = f2b(wq[i]); return; }
  i -= 16384;
  if (i < 16384) { wkb[i] = f2b(wk[i]); return; }
  i -= 16384;
  if (i < 16384) { wvb[i] = f2b(wv[i]); return; }
  i -= 16384;
  if (i < 32768) { w2b[i] = f2b(w2[i]); return; }
  i -= 32768;
  if (i < 131072) {               // posT[n][c] = rel_h[c,h] + rel_w[c,w], n=h*32+w
    int n = i >> 7, c = i & 127;
    int h = n >> 5, w = n & 31;
    posT[i] = f2b(relh[c * 32 + h] + relw[c * 32 + w]);
    return;
  }
  i -= 131072;
  if (i < 128) { float s = g1[i] * rsqrtf(v1[i] + 1e-5f); bnc[i] = s; bnc[128 + i] = b1[i] - m1[i] * s; return; }
  i -= 128;
  if (i < 256) { float s = g2[i] * rsqrtf(v2[i] + 1e-5f); bnc[256 + i] = s; bnc[512 + i] = b2[i] - m2[i] * s; return; }
}

// ---------------- K1: x1T[b][n][c] = silu(bn1(w1 @ x[b])) ----------------
// M=128 (c), K=256 (ci), N=1024 (n) per batch. Tile 128x128, BK=32, 4 waves 2x2.
__launch_bounds__(256)
__global__ void k_conv1(const float* __restrict__ x, const short* __restrict__ w1b,
                        const float* __restrict__ bnc, short* __restrict__ x1T) {
  __shared__ __align__(16) short Al[128 * 40];
  __shared__ __align__(16) short Bl[128 * 40];
  const int bx = blockIdx.x;
  const int b = bx >> 3;
  const int n0 = (bx & 7) << 7;
  const int tid = threadIdx.x;
  const int wid = tid >> 6, lane = tid & 63;
  const int wr = wid >> 1, wc = wid & 1;
  const int cpr = lane & 15, g = lane >> 4;
  f32x4 acc[4][4] = {};
  const float* xb = x + (size_t)b * (256 * 1024);
  for (int kk = 0; kk < 8; ++kk) {
    // A: w1b rows 0..127, k-chunk kk*32..+31  (512 x uint4)
#pragma unroll
    for (int it = 0; it < 2; ++it) {
      int f = tid + it * 256;
      int row = f >> 2, c8 = f & 3;
      *reinterpret_cast<uint4*>(&Al[row * 40 + c8 * 8]) =
          *reinterpret_cast<const uint4*>(&w1b[row * 256 + kk * 32 + c8 * 8]);
    }
    // B: x[b][ci][n] fp32, transpose into Bl[n][ci] bf16
#pragma unroll
    for (int it = 0; it < 4; ++it) {
      int f = tid + it * 256;
      int ci = f >> 5, c4 = f & 31;
      float4 v4 = *reinterpret_cast<const float4*>(&xb[(size_t)(kk * 32 + ci) * 1024 + n0 + c4 * 4]);
      int nb = c4 * 4;
      Bl[(nb + 0) * 40 + ci] = f2b(v4.x);
      Bl[(nb + 1) * 40 + ci] = f2b(v4.y);
      Bl[(nb + 2) * 40 + ci] = f2b(v4.z);
      Bl[(nb + 3) * 40 + ci] = f2b(v4.w);
    }
    __syncthreads();
    bf16x8 af[4], bfr[4];
#pragma unroll
    for (int mf = 0; mf < 4; ++mf)
      af[mf] = *reinterpret_cast<const bf16x8*>(&Al[(wr * 64 + mf * 16 + cpr) * 40 + g * 8]);
#pragma unroll
    for (int nf = 0; nf < 4; ++nf)
      bfr[nf] = *reinterpret_cast<const bf16x8*>(&Bl[(wc * 64 + nf * 16 + cpr) * 40 + g * 8]);
#pragma unroll
    for (int mf = 0; mf < 4; ++mf)
#pragma unroll
      for (int nf = 0; nf < 4; ++nf)
        acc[mf][nf] = MFMA(af[mf], bfr[nf], acc[mf][nf]);
    __syncthreads();
  }
#pragma unroll
  for (int mf = 0; mf < 4; ++mf) {
    int m0 = wr * 64 + mf * 16 + g * 4;
#pragma unroll
    for (int nf = 0; nf < 4; ++nf) {
      int n = n0 + wc * 64 + nf * 16 + cpr;
      union { short s[4]; uint2 u; } pk;
#pragma unroll
      for (int r = 0; r < 4; ++r) {
        int c = m0 + r;
        float z = acc[mf][nf][r] * bnc[c] + bnc[128 + c];
        pk.s[r] = f2b(z / (1.f + __expf(-z)));
      }
      *reinterpret_cast<uint2*>(&x1T[((size_t)b * 1024 + n) * 128 + m0]) = pk.u;
    }
  }
}

// ---------------- K2: q/k/v = W @ x1 + bias ----------------
// grid = b(32) x which(3) x ntile(8). qT/kT stored [B][N][C], v stored [B][C][N].
__launch_bounds__(256)
__global__ void k_qkv(const short* __restrict__ x1T, const short* __restrict__ wqb,
                      const short* __restrict__ wkb, const short* __restrict__ wvb,
                      const float* __restrict__ bq, const float* __restrict__ bk,
                      const float* __restrict__ bv,
                      short* __restrict__ qT, short* __restrict__ kT,
                      short* __restrict__ vv) {
  __shared__ __align__(16) short Al[128 * 40];
  __shared__ __align__(16) short Bl[128 * 40];
  const int bx = blockIdx.x;
  const int b = bx / 24;
  const int which = (bx >> 3) % 3;
  const int n0 = (bx & 7) << 7;
  const short* W = which == 0 ? wqb : which == 1 ? wkb : wvb;
  const float* bias = which == 0 ? bq : which == 1 ? bk : bv;
  const int tid = threadIdx.x;
  const int wid = tid >> 6, lane = tid & 63;
  const int wr = wid >> 1, wc = wid & 1;
  const int cpr = lane & 15, g = lane >> 4;
  f32x4 acc[4][4] = {};
  for (int kk = 0; kk < 4; ++kk) {
#pragma unroll
    for (int it = 0; it < 2; ++it) {
      int f = tid + it * 256;
      int row = f >> 2, c8 = f & 3;
      *reinterpret_cast<uint4*>(&Al[row * 40 + c8 * 8]) =
          *reinterpret_cast<const uint4*>(&W[row * 128 + kk * 32 + c8 * 8]);
      *reinterpret_cast<uint4*>(&Bl[row * 40 + c8 * 8]) =
          *reinterpret_cast<const uint4*>(&x1T[((size_t)b * 1024 + n0 + row) * 128 + kk * 32 + c8 * 8]);
    }
    __syncthreads();
    bf16x8 af[4], bfr[4];
#pragma unroll
    for (int mf = 0; mf < 4; ++mf)
      af[mf] = *reinterpret_cast<const bf16x8*>(&Al[(wr * 64 + mf * 16 + cpr) * 40 + g * 8]);
#pragma unroll
    for (int nf = 0; nf < 4; ++nf)
      bfr[nf] = *reinterpret_cast<const bf16x8*>(&Bl[(wc * 64 + nf * 16 + cpr) * 40 + g * 8]);
#pragma unroll
    for (int mf = 0; mf < 4; ++mf)
#pragma unroll
      for (int nf = 0; nf < 4; ++nf)
        acc[mf][nf] = MFMA(af[mf], bfr[nf], acc[mf][nf]);
    __syncthreads();
  }
#pragma unroll
  for (int mf = 0; mf < 4; ++mf) {
    int m0 = wr * 64 + mf * 16 + g * 4;
#pragma unroll
    for (int nf = 0; nf < 4; ++nf) {
      int n = n0 + wc * 64 + nf * 16 + cpr;
      if (which < 2) {
        union { short s[4]; uint2 u; } pk;
#pragma unroll
        for (int r = 0; r < 4; ++r)
          pk.s[r] = f2b(acc[mf][nf][r] + bias[m0 + r]);
        short* dst = which == 0 ? qT : kT;
        *reinterpret_cast<uint2*>(&dst[((size_t)b * 1024 + n) * 128 + m0]) = pk.u;
      } else {
#pragma unroll
        for (int r = 0; r < 4; ++r) {
          int c = m0 + r;
          vv[((size_t)b * 128 + c) * 1024 + n] = f2b(acc[mf][nf][r] + bias[c]);
        }
      }
    }
  }
}

// ---------------- K3: flash attention ----------------
// S = Qhat^T Khat, Qhat=[q;pos], Khat=[k;q] (inner 256). Online softmax over j.
// O^T[i,c] = sum_j P[i,j] V^T[j,c]. Block = (b, 64-row i-tile), 4 waves x 16 rows.
__launch_bounds__(256)
__global__ void k_attn(const short* __restrict__ qT, const short* __restrict__ kT,
                       const short* __restrict__ vv, const short* __restrict__ posT,
                       short* __restrict__ oT) {
  __shared__ __align__(16) short Kh[64 * 256];   // XOR-swizzled rows (khat / initially qhat)
  __shared__ __align__(16) short Vt[128 * 72];   // V[c][j] tile, padded rows
  __shared__ __align__(16) short Pl[4 * 16 * 72];// per-wave P tile [16][64], padded
  const int bx = blockIdx.x;
  const int b = bx >> 4;
  const int i0 = (bx & 15) << 6;
  const int tid = threadIdx.x;
  const int wid = tid >> 6, lane = tid & 63;
  const int cpr = lane & 15, g = lane >> 4;

  // stage Qhat rows i0..i0+63 into Kh (swizzled), then hoist to registers
  for (int f = tid; f < 64 * 32; f += 256) {
    int row = f >> 5, g8 = f & 31;
    const short* src = (g8 < 16)
        ? &qT[((size_t)b * 1024 + i0 + row) * 128 + g8 * 8]
        : &posT[(size_t)(i0 + row) * 128 + (g8 - 16) * 8];
    int sg = g8 ^ (row & 7);
    *reinterpret_cast<uint4*>(&Kh[row * 256 + sg * 8]) = *reinterpret_cast<const uint4*>(src);
  }
  __syncthreads();
  bf16x8 qf[8];
  {
    int row = wid * 16 + cpr;
#pragma unroll
    for (int kc = 0; kc < 8; ++kc) {
      int col = (kc * 32 + g * 8) ^ ((row & 7) << 3);
      qf[kc] = *reinterpret_cast<const bf16x8*>(&Kh[row * 256 + col]);
    }
  }
  __syncthreads();

  f32x4 oacc[8] = {};
  float mrow[4], lrow[4];
#pragma unroll
  for (int r = 0; r < 4; ++r) { mrow[r] = -3e38f; lrow[r] = 0.f; }

  for (int jt = 0; jt < 16; ++jt) {
    const int j0 = jt << 6;
    // stage Khat rows j0..j0+63: [0:128)=k, [128:256)=q  (swizzled)
    for (int f = tid; f < 64 * 32; f += 256) {
      int row = f >> 5, g8 = f & 31;
      const short* src = (g8 < 16)
          ? &kT[((size_t)b * 1024 + j0 + row) * 128 + g8 * 8]
          : &qT[((size_t)b * 1024 + j0 + row) * 128 + (g8 - 16) * 8];
      int sg = g8 ^ (row & 7);
      *reinterpret_cast<uint4*>(&Kh[row * 256 + sg * 8]) = *reinterpret_cast<const uint4*>(src);
    }
    // stage V tile: Vt[c][0..63] = v[b][c][j0..j0+63]
    for (int f = tid; f < 128 * 8; f += 256) {
      int c = f >> 3, g8 = f & 7;
      *reinterpret_cast<uint4*>(&Vt[c * 72 + g8 * 8]) =
          *reinterpret_cast<const uint4*>(&vv[((size_t)b * 128 + c) * 1024 + j0 + g8 * 8]);
    }
    __syncthreads();

    // S frags (wave rows = wid*16..+15, j = 64 cols)
    f32x4 s[4] = {};
#pragma unroll
    for (int kc = 0; kc < 8; ++kc) {
      bf16x8 a = qf[kc];
#pragma unroll
      for (int nf = 0; nf < 4; ++nf) {
        int row = nf * 16 + cpr;
        int col = (kc * 32 + g * 8) ^ ((row & 7) << 3);
        bf16x8 bb = *reinterpret_cast<const bf16x8*>(&Kh[row * 256 + col]);
        s[nf] = MFMA(a, bb, s[nf]);
      }
    }
    // online softmax; lane's rows are g*4+r
    float mnew[4], sc4[4];
#pragma unroll
    for (int r = 0; r < 4; ++r) {
      float mx = fmaxf(fmaxf(s[0][r], s[1][r]), fmaxf(s[2][r], s[3][r]));
#pragma unroll
      for (int off = 1; off < 16; off <<= 1)
        mx = fmaxf(mx, __shfl_xor(mx, off));
      mnew[r] = fmaxf(mrow[r], mx);
      sc4[r] = __expf(mrow[r] - mnew[r]);
    }
    float psum[4] = {0.f, 0.f, 0.f, 0.f};
#pragma unroll
    for (int nf = 0; nf < 4; ++nf)
#pragma unroll
      for (int r = 0; r < 4; ++r) {
        float p = __expf(s[nf][r] - mnew[r]);
        s[nf][r] = p;
        psum[r] += p;
      }
#pragma unroll
    for (int r = 0; r < 4; ++r) {
#pragma unroll
      for (int off = 1; off < 16; off <<= 1)
        psum[r] += __shfl_xor(psum[r], off);
      lrow[r] = lrow[r] * sc4[r] + psum[r];
      mrow[r] = mnew[r];
    }
#pragma unroll
    for (int cf = 0; cf < 8; ++cf)
#pragma unroll
      for (int r = 0; r < 4; ++r)
        oacc[cf][r] *= sc4[r];
    // P -> LDS (per-wave region), then PV
#pragma unroll
    for (int nf = 0; nf < 4; ++nf)
#pragma unroll
      for (int r = 0; r < 4; ++r)
        Pl[(wid * 16 + g * 4 + r) * 72 + nf * 16 + cpr] = f2b(s[nf][r]);
#pragma unroll
    for (int kc = 0; kc < 2; ++kc) {
      bf16x8 a = *reinterpret_cast<const bf16x8*>(&Pl[(wid * 16 + cpr) * 72 + kc * 32 + g * 8]);
#pragma unroll
      for (int cf = 0; cf < 8; ++cf) {
        bf16x8 bb = *reinterpret_cast<const bf16x8*>(&Vt[(cf * 16 + cpr) * 72 + kc * 32 + g * 8]);
        oacc[cf] = MFMA(a, bb, oacc[cf]);
      }
    }
    __syncthreads();
  }
  // epilogue: oT[b][i][c] = O/l
#pragma unroll
  for (int cf = 0; cf < 8; ++cf)
#pragma unroll
    for (int r = 0; r < 4; ++r) {
      int i = i0 + wid * 16 + g * 4 + r;
      int c = cf * 16 + cpr;
      oT[((size_t)b * 1024 + i) * 128 + c] = f2b(oacc[cf][r] / lrow[r]);
    }
}

// ---------------- K4: out = x + silu(bn2(w2 @ O)) ----------------
// grid = b(32) x mtile(2) x ntile(8). M=256, K=128, N=1024.
__launch_bounds__(256)
__global__ void k_conv2(const float* __restrict__ x, const short* __restrict__ w2b,
                        const short* __restrict__ oT, const float* __restrict__ bnc,
                        float* __restrict__ out) {
  __shared__ __align__(16) short Al[128 * 40];
  __shared__ __align__(16) short Bl[128 * 40];
  const int bx = blockIdx.x;
  const int b = bx >> 4;
  const int mt = (bx >> 3) & 1;
  const int n0 = (bx & 7) << 7;
  const int tid = threadIdx.x;
  const int wid = tid >> 6, lane = tid & 63;
  const int wr = wid >> 1, wc = wid & 1;
  const int cpr = lane & 15, g = lane >> 4;
  f32x4 acc[4][4] = {};
  for (int kk = 0; kk < 4; ++kk) {
#pragma unroll
    for (int it = 0; it < 2; ++it) {
      int f = tid + it * 256;
      int row = f >> 2, c8 = f & 3;
      *reinterpret_cast<uint4*>(&Al[row * 40 + c8 * 8]) =
          *reinterpret_cast<const uint4*>(&w2b[(size_t)(mt * 128 + row) * 128 + kk * 32 + c8 * 8]);
      *reinterpret_cast<uint4*>(&Bl[row * 40 + c8 * 8]) =
          *reinterpret_cast<const uint4*>(&oT[((size_t)b * 1024 + n0 + row) * 128 + kk * 32 + c8 * 8]);
    }
    __syncthreads();
    bf16x8 af[4], bfr[4];
#pragma unroll
    for (int mf = 0; mf < 4; ++mf)
      af[mf] = *reinterpret_cast<const bf16x8*>(&Al[(wr * 64 + mf * 16 + cpr) * 40 + g * 8]);
#pragma unroll
    for (int nf = 0; nf < 4; ++nf)
      bfr[nf] = *reinterpret_cast<const bf16x8*>(&Bl[(wc * 64 + nf * 16 + cpr) * 40 + g * 8]);
#pragma unroll
    for (int mf = 0; mf < 4; ++mf)
#pragma unroll
      for (int nf = 0; nf < 4; ++nf)
        acc[mf][nf] = MFMA(af[mf], bfr[nf], acc[mf][nf]);
    __syncthreads();
  }
#pragma unroll
  for (int mf = 0; mf < 4; ++mf) {
    int m0 = wr * 64 + mf * 16 + g * 4;
#pragma unroll
    for (int nf = 0; nf < 4; ++nf) {
      int n = n0 + wc * 64 + nf * 16 + cpr;
#pragma unroll
      for (int r = 0; r < 4; ++r) {
        int co = mt * 128 + m0 + r;
        float z = acc[mf][nf][r];
        float y = z * bnc[256 + co] + bnc[512 + co];
        float sl = y / (1.f + __expf(-y));
        size_t idx = ((size_t)b * 256 + co) * 1024 + n;
        out[idx] = x[idx] + sl;
      }
    }
  }
}

// ---------------- host ----------------
extern "C" void kernel_launch(void* const* d_in, const int* in_sizes, int n_in,
                              void* d_out, int out_size, void* d_ws, size_t ws_size,
                              hipStream_t stream) {
  (void)in_sizes; (void)n_in; (void)out_size; (void)ws_size;
  const float* x    = (const float*)d_in[0];
  const float* w1   = (const float*)d_in[1];
  const float* g1   = (const float*)d_in[2];
  const float* b1   = (const float*)d_in[3];
  const float* m1   = (const float*)d_in[4];
  const float* v1   = (const float*)d_in[5];
  const float* wq   = (const float*)d_in[6];
  const float* bq   = (const float*)d_in[7];
  const float* wk   = (const float*)d_in[8];
  const float* bk   = (const float*)d_in[9];
  const float* wv   = (const float*)d_in[10];
  const float* bv   = (const float*)d_in[11];
  const float* relh = (const float*)d_in[12];
  const float* relw = (const float*)d_in[13];
  const float* w2   = (const float*)d_in[14];
  const float* g2   = (const float*)d_in[15];
  const float* b2   = (const float*)d_in[16];
  const float* m2   = (const float*)d_in[17];
  const float* v2   = (const float*)d_in[18];
  float* out = (float*)d_out;

  char* ws = (char*)d_ws;
  const size_t OFF_W1B  = 0;                        // 65536
  const size_t OFF_WQB  = 65536;                    // 32768
  const size_t OFF_WKB  = 98304;                    // 32768
  const size_t OFF_WVB  = 131072;                   // 32768
  const size_t OFF_W2B  = 163840;                   // 65536
  const size_t OFF_POST = 229376;                   // 262144
  const size_t OFF_BN   = 491520;                   // 3072
  const size_t OFF_X1T  = 494592;                   // 8388608 (also reused as oT)
  const size_t OFF_QT   = OFF_X1T + 8388608;
  const size_t OFF_KT   = OFF_QT  + 8388608;
  const size_t OFF_V    = OFF_KT  + 8388608;
  const size_t OFF_OT   = OFF_X1T;                  // alias: x1T dead after k_qkv

  short* w1b  = (short*)(ws + OFF_W1B);
  short* wqb  = (short*)(ws + OFF_WQB);
  short* wkb  = (short*)(ws + OFF_WKB);
  short* wvb  = (short*)(ws + OFF_WVB);
  short* w2b  = (short*)(ws + OFF_W2B);
  short* posT = (short*)(ws + OFF_POST);
  float* bnc  = (float*)(ws + OFF_BN);
  short* x1T  = (short*)(ws + OFF_X1T);
  short* qT   = (short*)(ws + OFF_QT);
  short* kT   = (short*)(ws + OFF_KT);
  short* vv   = (short*)(ws + OFF_V);
  short* oT   = (short*)(ws + OFF_OT);

  k_prep<<<962, 256, 0, stream>>>(w1, wq, wk, wv, w2, relh, relw,
                                  g1, b1, m1, v1, g2, b2, m2, v2,
                                  w1b, wqb, wkb, wvb, w2b, posT, bnc);
  k_conv1<<<256, 256, 0, stream>>>(x, w1b, bnc, x1T);
  k_qkv<<<768, 256, 0, stream>>>(x1T, wqb, wkb, wvb, bq, bk, bv, qT, kT, vv);
  k_attn<<<512, 256, 0, stream>>>(qT, kT, vv, posT, oT);
  k_conv2<<<512, 256, 0, stream>>>(x, w2b, oT, bnc, out);
}